// Round 2
// baseline (784.850 us; speedup 1.0000x reference)
//
#include <hip/hip_runtime.h>
#include <math.h>

#define S_CAP   27
#define NCELLS  4096
#define MAXNB   128
#define CUT     5.0f

// ---------------- K1: wrap coords, COM, min/max, shifts, header ----------------
__global__ __launch_bounds__(256)
void k1_pre(const int* __restrict__ period, const float* __restrict__ coor,
            const float* __restrict__ cell, const float* __restrict__ mass,
            int* hdr_i, float* hdr_f, float* shifts, float* xf, int n)
{
    #pragma clang fp contract(off)
    __shared__ double rs[256 * 4];
    __shared__ float  redf[256 * 3];
    __shared__ float  s_com[3], s_m2[3], s_max[3];
    int t = threadIdx.x;

    float c[3][3];
    #pragma unroll
    for (int i = 0; i < 3; i++)
        #pragma unroll
        for (int j = 0; j < 3; j++) c[i][j] = cell[3 * i + j];

    // analytic inverse (exact for diagonal cell; matches LAPACK there)
    float a00 = c[1][1]*c[2][2] - c[1][2]*c[2][1];
    float a01 = c[0][2]*c[2][1] - c[0][1]*c[2][2];
    float a02 = c[0][1]*c[1][2] - c[0][2]*c[1][1];
    float a10 = c[1][2]*c[2][0] - c[1][0]*c[2][2];
    float a11 = c[0][0]*c[2][2] - c[0][2]*c[2][0];
    float a12 = c[0][2]*c[1][0] - c[0][0]*c[1][2];
    float a20 = c[1][0]*c[2][1] - c[1][1]*c[2][0];
    float a21 = c[0][1]*c[2][0] - c[0][0]*c[2][1];
    float a22 = c[0][0]*c[1][1] - c[0][1]*c[1][0];
    float det = c[0][0]*a00 + c[0][1]*a10 + c[0][2]*a20;
    float inv[3][3] = {{a00/det, a01/det, a02/det},
                       {a10/det, a11/det, a12/det},
                       {a20/det, a21/det, a22/det}};

    // fractional coords of atom 0 (computed redundantly by every thread)
    float f0[3];
    #pragma unroll
    for (int d = 0; d < 3; d++)
        f0[d] = coor[0]*inv[0][d] + coor[1]*inv[1][d] + coor[2]*inv[2][d];

    // pass 1: wrap into cell, store cartesian, accumulate mass sums (fp64)
    double sm = 0.0, sx = 0.0, sy = 0.0, sz = 0.0;
    for (int i = t; i < n; i += 256) {
        float p0 = coor[3*i], p1 = coor[3*i+1], p2 = coor[3*i+2];
        float ic[3], w[3], x[3];
        #pragma unroll
        for (int d = 0; d < 3; d++)
            ic[d] = p0*inv[0][d] + p1*inv[1][d] + p2*inv[2][d];
        #pragma unroll
        for (int d = 0; d < 3; d++)
            w[d] = ic[d] - rintf(ic[d] - f0[d]);
        #pragma unroll
        for (int d = 0; d < 3; d++)
            x[d] = w[0]*c[0][d] + w[1]*c[1][d] + w[2]*c[2][d];
        xf[3*i] = x[0]; xf[3*i+1] = x[1]; xf[3*i+2] = x[2];
        float m = mass[i];
        sm += (double)m;
        sx += (double)m * (double)x[0];
        sy += (double)m * (double)x[1];
        sz += (double)m * (double)x[2];
    }
    rs[t] = sm; rs[256+t] = sx; rs[512+t] = sy; rs[768+t] = sz;
    __syncthreads();
    for (int off = 128; off > 0; off >>= 1) {
        if (t < off) {
            rs[t]       += rs[t+off];
            rs[256+t]   += rs[256+t+off];
            rs[512+t]   += rs[512+t+off];
            rs[768+t]   += rs[768+t+off];
        }
        __syncthreads();
    }
    if (t == 0) {
        float den = (float)rs[0];
        s_com[0] = ((float)rs[256]) / den;
        s_com[1] = ((float)rs[512]) / den;
        s_com[2] = ((float)rs[768]) / den;
    }
    __syncthreads();
    float com0 = s_com[0], com1 = s_com[1], com2 = s_com[2];

    // pass 2: subtract COM, per-dim min
    float mn0 = __builtin_inff(), mn1 = __builtin_inff(), mn2 = __builtin_inff();
    for (int i = t; i < n; i += 256) {
        float v0 = xf[3*i]   - com0;
        float v1 = xf[3*i+1] - com1;
        float v2 = xf[3*i+2] - com2;
        xf[3*i] = v0; xf[3*i+1] = v1; xf[3*i+2] = v2;
        mn0 = fminf(mn0, v0); mn1 = fminf(mn1, v1); mn2 = fminf(mn2, v2);
    }
    redf[t] = mn0; redf[256+t] = mn1; redf[512+t] = mn2;
    __syncthreads();
    for (int off = 128; off > 0; off >>= 1) {
        if (t < off) {
            redf[t]     = fminf(redf[t],     redf[t+off]);
            redf[256+t] = fminf(redf[256+t], redf[256+t+off]);
            redf[512+t] = fminf(redf[512+t], redf[512+t+off]);
        }
        __syncthreads();
    }
    if (t == 0) {
        s_m2[0] = (redf[0]   - CUT) - 1e-6f;
        s_m2[1] = (redf[256] - CUT) - 1e-6f;
        s_m2[2] = (redf[512] - CUT) - 1e-6f;
    }
    __syncthreads();
    float m20 = s_m2[0], m21 = s_m2[1], m22 = s_m2[2];

    // pass 3: shift to positive box, per-dim max
    float mx0 = -__builtin_inff(), mx1 = -__builtin_inff(), mx2 = -__builtin_inff();
    for (int i = t; i < n; i += 256) {
        float v0 = xf[3*i]   - m20;
        float v1 = xf[3*i+1] - m21;
        float v2 = xf[3*i+2] - m22;
        xf[3*i] = v0; xf[3*i+1] = v1; xf[3*i+2] = v2;
        mx0 = fmaxf(mx0, v0); mx1 = fmaxf(mx1, v1); mx2 = fmaxf(mx2, v2);
    }
    redf[t] = mx0; redf[256+t] = mx1; redf[512+t] = mx2;
    __syncthreads();
    for (int off = 128; off > 0; off >>= 1) {
        if (t < off) {
            redf[t]     = fmaxf(redf[t],     redf[t+off]);
            redf[256+t] = fmaxf(redf[256+t], redf[256+t+off]);
            redf[512+t] = fmaxf(redf[512+t], redf[512+t+off]);
        }
        __syncthreads();
    }
    if (t == 0) {
        s_max[0] = redf[0]   + CUT;
        s_max[1] = redf[256] + CUT;
        s_max[2] = redf[512] + CUT;
        float maxc0 = s_max[0], maxc1 = s_max[1], maxc2 = s_max[2];
        float mcell0 = ceilf(maxc0 / CUT);
        float mcell1 = ceilf(maxc1 / CUT);
        float f10 = mcell1 * mcell0;
        int nr[3];
        for (int j = 0; j < 3; j++) {
            float v = __builtin_inff();
            for (int i = 0; i < 3; i++) {
                float q = CUT / fabsf(c[i][j]);   // IEEE: /0 -> inf
                v = fminf(v, q);
            }
            nr[j] = (int)ceilf(v);
            nr[j] *= period[j];
        }
        int nsz0 = 2*nr[0]+1, nsz1 = 2*nr[1]+1, nsz2 = 2*nr[2]+1;
        int S = nsz0 * nsz1 * nsz2;
        if (S > S_CAP) S = S_CAP;   // capacity guard (27 for this input)
        hdr_i[0] = S;
        hdr_i[3] = -nr[0]; hdr_i[4] = -nr[1]; hdr_i[5] = -nr[2];
        hdr_i[6] = nsz0;   hdr_i[7] = nsz1;   hdr_i[8] = nsz2;
        hdr_i[9]  = (int)mcell0;
        hdr_i[10] = (int)f10;
        hdr_f[0] = maxc0; hdr_f[1] = maxc1; hdr_f[2] = maxc2;
        hdr_f[3] = f10;   hdr_f[4] = mcell0;
    }
    __syncthreads();
    int S = hdr_i[0];
    if (t < S) {
        int n1 = hdr_i[7], n2 = hdr_i[8];
        int i0 = t / (n1 * n2);
        int rem = t - i0 * n1 * n2;
        int i1 = rem / n2;
        int i2 = rem - i1 * n2;
        float fx = (float)(hdr_i[3] + i0);
        float fy = (float)(hdr_i[4] + i1);
        float fz = (float)(hdr_i[5] + i2);
        #pragma unroll
        for (int d = 0; d < 3; d++)
            shifts[3*t + d] = fx*c[0][d] + fy*c[1][d] + fz*c[2][d];
    }
}

// ---------------- K2: generate periodic images + keep mask ----------------
__global__ __launch_bounds__(256)
void k2_img(const int* __restrict__ hdr_i, const float* __restrict__ hdr_f,
            const float* __restrict__ shifts, const float* __restrict__ xf,
            float* __restrict__ img, int* __restrict__ keep, int n, int SN)
{
    #pragma clang fp contract(off)
    int g = blockIdx.x * 256 + threadIdx.x;
    if (g >= SN) return;
    int S = hdr_i[0];
    int sn = S * n;
    if (g >= sn) { keep[g] = 0; return; }
    int s = g / n;
    int a = g - s * n;
    float i0 = xf[3*a]   + shifts[3*s];
    float i1 = xf[3*a+1] + shifts[3*s+1];
    float i2 = xf[3*a+2] + shifts[3*s+2];
    img[3*g] = i0; img[3*g+1] = i1; img[3*g+2] = i2;
    bool k = (i0 > 0.0f) && (i0 < hdr_f[0]) &&
             (i1 > 0.0f) && (i1 < hdr_f[1]) &&
             (i2 > 0.0f) && (i2 < hdr_f[2]);
    keep[g] = k ? 1 : 0;
}

// ---------------- K3: stable compaction of kept images (single block) ----------------
__global__ __launch_bounds__(1024)
void k3_compact(int* hdr_i, const float* __restrict__ hdr_f,
                const float* __restrict__ img, const int* __restrict__ keep,
                float* __restrict__ imgc, int* __restrict__ jatom,
                int* __restrict__ jshift, int* __restrict__ jcell,
                int* __restrict__ ccount, int* __restrict__ ccur,
                int n, int SN)
{
    #pragma clang fp contract(off)
    __shared__ int sarr[1024];
    int t = threadIdx.x;
    int CH = (SN + 1023) >> 10;
    int base = t * CH;
    int lsum = 0;
    for (int e = 0; e < CH; e++) {
        int g = base + e;
        if (g < SN) lsum += keep[g];
    }
    sarr[t] = lsum;
    __syncthreads();
    for (int off = 1; off < 1024; off <<= 1) {
        int v = (t >= off) ? sarr[t - off] : 0;
        __syncthreads();
        sarr[t] += v;
        __syncthreads();
    }
    int excl = sarr[t] - lsum;
    int M = sarr[1023];
    float f10 = hdr_f[3], mc0 = hdr_f[4];
    int pos = excl;
    for (int e = 0; e < CH; e++) {
        int g = base + e;
        if (g >= SN) break;
        if (keep[g]) {
            int j = pos++;
            float i0 = img[3*g], i1 = img[3*g+1], i2 = img[3*g+2];
            imgc[3*j] = i0; imgc[3*j+1] = i1; imgc[3*j+2] = i2;
            int s = g / n;
            jshift[j] = s;
            jatom[j]  = g - s * n;
            float fc0 = floorf(i0 / CUT);
            float fc1 = floorf(i1 / CUT);
            float fc2 = floorf(i2 / CUT);
            float cf = fc2 * f10 + fc1 * mc0 + fc0;
            int ci = (int)cf;
            if (ci < 0) ci = 0;
            if (ci >= NCELLS) ci = NCELLS - 1;
            jcell[j] = ci;
        }
    }
    if (t == 0) hdr_i[1] = M;
    for (int cdx = t; cdx < NCELLS; cdx += 1024) { ccount[cdx] = 0; ccur[cdx] = 0; }
}

// ---------------- K4: histogram images per cell ----------------
__global__ __launch_bounds__(256)
void k4_count(const int* __restrict__ hdr_i, const int* __restrict__ jcell,
              int* __restrict__ ccount, int SN)
{
    int j = blockIdx.x * 256 + threadIdx.x;
    if (j >= SN) return;
    if (j >= hdr_i[1]) return;
    atomicAdd(&ccount[jcell[j]], 1);
}

// ---------------- K5a: exclusive scan of cell counts (single block) ----------------
__global__ __launch_bounds__(1024)
void k5_scan(const int* __restrict__ ccount, int* __restrict__ cstart)
{
    __shared__ int sarr[1024];
    int t = threadIdx.x;
    int b = t * 4;
    int v0 = ccount[b], v1 = ccount[b+1], v2 = ccount[b+2], v3 = ccount[b+3];
    int lsum = v0 + v1 + v2 + v3;
    sarr[t] = lsum;
    __syncthreads();
    for (int off = 1; off < 1024; off <<= 1) {
        int v = (t >= off) ? sarr[t - off] : 0;
        __syncthreads();
        sarr[t] += v;
        __syncthreads();
    }
    int excl = sarr[t] - lsum;
    cstart[b]   = excl;
    cstart[b+1] = excl + v0;
    cstart[b+2] = excl + v0 + v1;
    cstart[b+3] = excl + v0 + v1 + v2;
    if (t == 1023) cstart[NCELLS] = sarr[1023];
}

// ---------------- K5b: fill buckets (unordered; k8 sorts by j later) ----------------
__global__ __launch_bounds__(256)
void k5b_fill(const int* __restrict__ hdr_i, const int* __restrict__ jcell,
              const int* __restrict__ cstart, int* __restrict__ ccur,
              int* __restrict__ bucket, int SN)
{
    int j = blockIdx.x * 256 + threadIdx.x;
    if (j >= SN) return;
    if (j >= hdr_i[1]) return;
    int c = jcell[j];
    int w = cstart[c] + atomicAdd(&ccur[c], 1);
    bucket[w] = j;
}

// ---------------- K6: per-atom pair count ----------------
__global__ __launch_bounds__(256)
void k6_count(const int* __restrict__ hdr_i, const float* __restrict__ xf,
              const float* __restrict__ imgc, const int* __restrict__ cstart,
              const int* __restrict__ bucket, int* __restrict__ npair, int n)
{
    #pragma clang fp contract(off)
    int i = blockIdx.x * 256 + threadIdx.x;
    if (i >= n) return;
    int mci = hdr_i[9], f10i = hdr_i[10];
    float x0 = xf[3*i], x1 = xf[3*i+1], x2 = xf[3*i+2];
    int o0 = (int)floorf(x0 / CUT);
    int o1 = (int)floorf(x1 / CUT);
    int o2 = (int)floorf(x2 / CUT);
    int cnt = 0;
    for (int dz = -1; dz <= 1; dz++)
        for (int dy = -1; dy <= 1; dy++)
            for (int dx = -1; dx <= 1; dx++) {
                int nc = (o2+dz)*f10i + (o1+dy)*mci + (o0+dx);
                if (nc < 0 || nc >= NCELLS) continue;
                int b0 = cstart[nc], b1 = cstart[nc+1];
                for (int b = b0; b < b1; b++) {
                    int j = bucket[b];
                    float dxx = x0 - imgc[3*j];
                    float dyy = x1 - imgc[3*j+1];
                    float dzz = x2 - imgc[3*j+2];
                    float ss = dxx*dxx + dyy*dyy + dzz*dzz;
                    float dd = sqrtf(ss);
                    if (dd < CUT && dd > 0.001f) cnt++;
                }
            }
    npair[i] = cnt;
}

// ---------------- K7: exclusive scan over atoms (single block) ----------------
__global__ __launch_bounds__(1024)
void k7_scan(int* hdr_i, const int* __restrict__ npair, int* __restrict__ pstart, int n)
{
    __shared__ int sarr[1024];
    int t = threadIdx.x;
    int CH = (n + 1023) >> 10;
    int base = t * CH;
    int lsum = 0;
    for (int e = 0; e < CH; e++) {
        int g = base + e;
        if (g < n) lsum += npair[g];
    }
    sarr[t] = lsum;
    __syncthreads();
    for (int off = 1; off < 1024; off <<= 1) {
        int v = (t >= off) ? sarr[t - off] : 0;
        __syncthreads();
        sarr[t] += v;
        __syncthreads();
    }
    int run = sarr[t] - lsum;
    for (int e = 0; e < CH; e++) {
        int g = base + e;
        if (g < n) { pstart[g] = run; run += npair[g]; }
    }
    if (t == 1023) pstart[n] = sarr[1023];
    if (t == 0)    hdr_i[2]  = sarr[1023];
}

// ---------------- K8: emit pairs sorted by image index j (float32 out) ----------------
__global__ __launch_bounds__(64)
void k8_emit(const int* __restrict__ hdr_i, const float* __restrict__ xf,
             const float* __restrict__ imgc, const int* __restrict__ jatom,
             const int* __restrict__ jshift, const float* __restrict__ shifts,
             const int* __restrict__ cstart, const int* __restrict__ bucket,
             const int* __restrict__ pstart, float* __restrict__ out,
             int n, int P)
{
    #pragma clang fp contract(off)
    __shared__ int lst[MAXNB * 64];
    int t = threadIdx.x;
    int i = blockIdx.x * 64 + t;
    if (i >= n) return;
    int mci = hdr_i[9], f10i = hdr_i[10];
    float x0 = xf[3*i], x1 = xf[3*i+1], x2 = xf[3*i+2];
    int o0 = (int)floorf(x0 / CUT);
    int o1 = (int)floorf(x1 / CUT);
    int o2 = (int)floorf(x2 / CUT);
    int cnt = 0;
    for (int dz = -1; dz <= 1; dz++)
        for (int dy = -1; dy <= 1; dy++)
            for (int dx = -1; dx <= 1; dx++) {
                int nc = (o2+dz)*f10i + (o1+dy)*mci + (o0+dx);
                if (nc < 0 || nc >= NCELLS) continue;
                int b0 = cstart[nc], b1 = cstart[nc+1];
                for (int b = b0; b < b1; b++) {
                    int j = bucket[b];
                    float dxx = x0 - imgc[3*j];
                    float dyy = x1 - imgc[3*j+1];
                    float dzz = x2 - imgc[3*j+2];
                    float ss = dxx*dxx + dyy*dyy + dzz*dzz;
                    float dd = sqrtf(ss);
                    if (dd < CUT && dd > 0.001f) {
                        if (cnt < MAXNB) lst[cnt * 64 + t] = j;
                        cnt++;
                    }
                }
            }
    if (cnt > MAXNB) cnt = MAXNB;
    // insertion sort by j (reference order = ascending kept-image index)
    for (int r = 1; r < cnt; r++) {
        int key = lst[r * 64 + t];
        int q = r - 1;
        while (q >= 0 && lst[q * 64 + t] > key) {
            lst[(q + 1) * 64 + t] = lst[q * 64 + t];
            q--;
        }
        lst[(q + 1) * 64 + t] = key;
    }
    int base = pstart[i];
    for (int r = 0; r < cnt; r++) {
        int p = base + r;
        if (p >= P) break;
        int j = lst[r * 64 + t];
        out[p]     = (float)i;
        out[P + p] = (float)jatom[j];
        int sp = jshift[j];
        out[2*P + 3*p]     = shifts[3*sp];
        out[2*P + 3*p + 1] = shifts[3*sp + 1];
        out[2*P + 3*p + 2] = shifts[3*sp + 2];
    }
}

extern "C" void kernel_launch(void* const* d_in, const int* in_sizes, int n_in,
                              void* d_out, int out_size, void* d_ws, size_t ws_size,
                              hipStream_t stream)
{
    const int*   period = (const int*)d_in[0];
    const float* coor   = (const float*)d_in[1];
    const float* cell   = (const float*)d_in[2];
    const float* mass   = (const float*)d_in[3];
    float* out = (float*)d_out;

    int n  = in_sizes[1] / 3;       // 2744
    int SN = S_CAP * n;             // 74088
    int P  = out_size / 5;          // pairs: neigh_list (2,P) + shifts (P,3)

    char* w = (char*)d_ws;
    size_t off = 0;
    auto alloc_f = [&](size_t cnt) -> float* { float* p = (float*)(w + off); off += cnt * 4; return p; };
    auto alloc_i = [&](size_t cnt) -> int*   { int*   p = (int*)  (w + off); off += cnt * 4; return p; };

    int*   hdr_i  = alloc_i(16);
    float* hdr_f  = alloc_f(16);
    float* shifts = alloc_f(3 * S_CAP);
    float* xf     = alloc_f(3 * (size_t)n);
    float* img    = alloc_f(3 * (size_t)SN);
    int*   keep   = alloc_i(SN);
    int*   jatom  = alloc_i(SN);
    int*   jshf   = alloc_i(SN);
    int*   jcell  = alloc_i(SN);
    float* imgc   = alloc_f(3 * (size_t)SN);
    int*   ccount = alloc_i(NCELLS);
    int*   ccur   = alloc_i(NCELLS);
    int*   cstart = alloc_i(NCELLS + 1);
    int*   bucket = alloc_i(SN);
    int*   npair  = alloc_i(n);
    int*   pstart = alloc_i(n + 1);
    (void)ws_size; (void)n_in;

    hipMemsetAsync(d_out, 0, (size_t)out_size * 4, stream);

    hipLaunchKernelGGL(k1_pre,     dim3(1),              dim3(256),  0, stream,
                       period, coor, cell, mass, hdr_i, hdr_f, shifts, xf, n);
    hipLaunchKernelGGL(k2_img,     dim3((SN+255)/256),   dim3(256),  0, stream,
                       hdr_i, hdr_f, shifts, xf, img, keep, n, SN);
    hipLaunchKernelGGL(k3_compact, dim3(1),              dim3(1024), 0, stream,
                       hdr_i, hdr_f, img, keep, imgc, jatom, jshf, jcell, ccount, ccur, n, SN);
    hipLaunchKernelGGL(k4_count,   dim3((SN+255)/256),   dim3(256),  0, stream,
                       hdr_i, jcell, ccount, SN);
    hipLaunchKernelGGL(k5_scan,    dim3(1),              dim3(1024), 0, stream,
                       ccount, cstart);
    hipLaunchKernelGGL(k5b_fill,   dim3((SN+255)/256),   dim3(256),  0, stream,
                       hdr_i, jcell, cstart, ccur, bucket, SN);
    hipLaunchKernelGGL(k6_count,   dim3((n+255)/256),    dim3(256),  0, stream,
                       hdr_i, xf, imgc, cstart, bucket, npair, n);
    hipLaunchKernelGGL(k7_scan,    dim3(1),              dim3(1024), 0, stream,
                       hdr_i, npair, pstart, n);
    hipLaunchKernelGGL(k8_emit,    dim3((n+63)/64),      dim3(64),   0, stream,
                       hdr_i, xf, imgc, jatom, jshf, shifts, cstart, bucket, pstart,
                       out, n, P);
}

// Round 3
// 228.091 us; speedup vs baseline: 3.4409x; 3.4409x over previous
//
#include <hip/hip_runtime.h>
#include <math.h>

#define S_CAP   27
#define NCELLS  4096
#define MAXNB   128
#define CUT     5.0f

// ---------------- K1: wrap coords, COM, min/max, shifts, header ----------------
__global__ __launch_bounds__(256)
void k1_pre(const int* __restrict__ period, const float* __restrict__ coor,
            const float* __restrict__ cell, const float* __restrict__ mass,
            int* hdr_i, float* hdr_f, float* shifts, float* xf, int n)
{
    #pragma clang fp contract(off)
    __shared__ double rs[256 * 4];
    __shared__ float  redf[256 * 3];
    __shared__ float  s_com[3], s_m2[3], s_max[3];
    int t = threadIdx.x;

    float c[3][3];
    #pragma unroll
    for (int i = 0; i < 3; i++)
        #pragma unroll
        for (int j = 0; j < 3; j++) c[i][j] = cell[3 * i + j];

    // analytic inverse (exact for diagonal cell)
    float a00 = c[1][1]*c[2][2] - c[1][2]*c[2][1];
    float a01 = c[0][2]*c[2][1] - c[0][1]*c[2][2];
    float a02 = c[0][1]*c[1][2] - c[0][2]*c[1][1];
    float a10 = c[1][2]*c[2][0] - c[1][0]*c[2][2];
    float a11 = c[0][0]*c[2][2] - c[0][2]*c[2][0];
    float a12 = c[0][2]*c[1][0] - c[0][0]*c[1][2];
    float a20 = c[1][0]*c[2][1] - c[1][1]*c[2][0];
    float a21 = c[0][1]*c[2][0] - c[0][0]*c[2][1];
    float a22 = c[0][0]*c[1][1] - c[0][1]*c[1][0];
    float det = c[0][0]*a00 + c[0][1]*a10 + c[0][2]*a20;
    float inv[3][3] = {{a00/det, a01/det, a02/det},
                       {a10/det, a11/det, a12/det},
                       {a20/det, a21/det, a22/det}};

    float f0[3];
    #pragma unroll
    for (int d = 0; d < 3; d++)
        f0[d] = coor[0]*inv[0][d] + coor[1]*inv[1][d] + coor[2]*inv[2][d];

    // pass 1: wrap into cell, store cartesian, accumulate mass sums (fp64)
    double sm = 0.0, sx = 0.0, sy = 0.0, sz = 0.0;
    for (int i = t; i < n; i += 256) {
        float p0 = coor[3*i], p1 = coor[3*i+1], p2 = coor[3*i+2];
        float ic[3], w[3], x[3];
        #pragma unroll
        for (int d = 0; d < 3; d++)
            ic[d] = p0*inv[0][d] + p1*inv[1][d] + p2*inv[2][d];
        #pragma unroll
        for (int d = 0; d < 3; d++)
            w[d] = ic[d] - rintf(ic[d] - f0[d]);
        #pragma unroll
        for (int d = 0; d < 3; d++)
            x[d] = w[0]*c[0][d] + w[1]*c[1][d] + w[2]*c[2][d];
        xf[3*i] = x[0]; xf[3*i+1] = x[1]; xf[3*i+2] = x[2];
        float m = mass[i];
        sm += (double)m;
        sx += (double)m * (double)x[0];
        sy += (double)m * (double)x[1];
        sz += (double)m * (double)x[2];
    }
    rs[t] = sm; rs[256+t] = sx; rs[512+t] = sy; rs[768+t] = sz;
    __syncthreads();
    for (int off = 128; off > 0; off >>= 1) {
        if (t < off) {
            rs[t]       += rs[t+off];
            rs[256+t]   += rs[256+t+off];
            rs[512+t]   += rs[512+t+off];
            rs[768+t]   += rs[768+t+off];
        }
        __syncthreads();
    }
    if (t == 0) {
        float den = (float)rs[0];
        s_com[0] = ((float)rs[256]) / den;
        s_com[1] = ((float)rs[512]) / den;
        s_com[2] = ((float)rs[768]) / den;
    }
    __syncthreads();
    float com0 = s_com[0], com1 = s_com[1], com2 = s_com[2];

    // pass 2: subtract COM, per-dim min
    float mn0 = __builtin_inff(), mn1 = __builtin_inff(), mn2 = __builtin_inff();
    for (int i = t; i < n; i += 256) {
        float v0 = xf[3*i]   - com0;
        float v1 = xf[3*i+1] - com1;
        float v2 = xf[3*i+2] - com2;
        xf[3*i] = v0; xf[3*i+1] = v1; xf[3*i+2] = v2;
        mn0 = fminf(mn0, v0); mn1 = fminf(mn1, v1); mn2 = fminf(mn2, v2);
    }
    redf[t] = mn0; redf[256+t] = mn1; redf[512+t] = mn2;
    __syncthreads();
    for (int off = 128; off > 0; off >>= 1) {
        if (t < off) {
            redf[t]     = fminf(redf[t],     redf[t+off]);
            redf[256+t] = fminf(redf[256+t], redf[256+t+off]);
            redf[512+t] = fminf(redf[512+t], redf[512+t+off]);
        }
        __syncthreads();
    }
    if (t == 0) {
        s_m2[0] = (redf[0]   - CUT) - 1e-6f;
        s_m2[1] = (redf[256] - CUT) - 1e-6f;
        s_m2[2] = (redf[512] - CUT) - 1e-6f;
    }
    __syncthreads();
    float m20 = s_m2[0], m21 = s_m2[1], m22 = s_m2[2];

    // pass 3: shift to positive box, per-dim max
    float mx0 = -__builtin_inff(), mx1 = -__builtin_inff(), mx2 = -__builtin_inff();
    for (int i = t; i < n; i += 256) {
        float v0 = xf[3*i]   - m20;
        float v1 = xf[3*i+1] - m21;
        float v2 = xf[3*i+2] - m22;
        xf[3*i] = v0; xf[3*i+1] = v1; xf[3*i+2] = v2;
        mx0 = fmaxf(mx0, v0); mx1 = fmaxf(mx1, v1); mx2 = fmaxf(mx2, v2);
    }
    redf[t] = mx0; redf[256+t] = mx1; redf[512+t] = mx2;
    __syncthreads();
    for (int off = 128; off > 0; off >>= 1) {
        if (t < off) {
            redf[t]     = fmaxf(redf[t],     redf[t+off]);
            redf[256+t] = fmaxf(redf[256+t], redf[256+t+off]);
            redf[512+t] = fmaxf(redf[512+t], redf[512+t+off]);
        }
        __syncthreads();
    }
    if (t == 0) {
        float maxc0 = redf[0]   + CUT;
        float maxc1 = redf[256] + CUT;
        float maxc2 = redf[512] + CUT;
        float mcell0 = ceilf(maxc0 / CUT);
        float mcell1 = ceilf(maxc1 / CUT);
        float f10 = mcell1 * mcell0;
        int nr[3];
        for (int j = 0; j < 3; j++) {
            float v = __builtin_inff();
            for (int i = 0; i < 3; i++) {
                float q = CUT / fabsf(c[i][j]);   // IEEE: /0 -> inf
                v = fminf(v, q);
            }
            nr[j] = (int)ceilf(v);
            nr[j] *= period[j];
        }
        int nsz0 = 2*nr[0]+1, nsz1 = 2*nr[1]+1, nsz2 = 2*nr[2]+1;
        int S = nsz0 * nsz1 * nsz2;
        if (S > S_CAP) S = S_CAP;
        hdr_i[0] = S;
        hdr_i[3] = -nr[0]; hdr_i[4] = -nr[1]; hdr_i[5] = -nr[2];
        hdr_i[6] = nsz0;   hdr_i[7] = nsz1;   hdr_i[8] = nsz2;
        hdr_i[9]  = (int)mcell0;
        hdr_i[10] = (int)f10;
        hdr_f[0] = maxc0; hdr_f[1] = maxc1; hdr_f[2] = maxc2;
        hdr_f[3] = f10;   hdr_f[4] = mcell0;
        s_max[0] = maxc0;  // reuse smem just to keep shape (unused below)
    }
    __syncthreads();
    int S = hdr_i[0];
    if (t < S) {
        int n1 = hdr_i[7], n2 = hdr_i[8];
        int i0 = t / (n1 * n2);
        int rem = t - i0 * n1 * n2;
        int i1 = rem / n2;
        int i2 = rem - i1 * n2;
        float fx = (float)(hdr_i[3] + i0);
        float fy = (float)(hdr_i[4] + i1);
        float fz = (float)(hdr_i[5] + i2);
        #pragma unroll
        for (int d = 0; d < 3; d++)
            shifts[3*t + d] = fx*c[0][d] + fy*c[1][d] + fz*c[2][d];
    }
}

// ---------------- K3: on-the-fly image gen + stable compaction + cell histogram ----------------
__global__ __launch_bounds__(1024)
void k3_compact(int* hdr_i, const float* __restrict__ hdr_f,
                const float* __restrict__ shifts, const float* __restrict__ xf,
                float* __restrict__ imgc, int* __restrict__ jatom,
                int* __restrict__ jshift, int* __restrict__ jcell,
                int* __restrict__ ccount, int* __restrict__ ccur,
                int n, int SN)
{
    #pragma clang fp contract(off)
    __shared__ int sarr[1024];
    int t = threadIdx.x;
    for (int c = t; c < NCELLS; c += 1024) { ccount[c] = 0; ccur[c] = 0; }
    int S = hdr_i[0];
    int sn = S * n;
    float bx0 = hdr_f[0], bx1 = hdr_f[1], bx2 = hdr_f[2];
    float f10 = hdr_f[3], mc0 = hdr_f[4];
    int CH = (SN + 1023) >> 10;
    int base = t * CH;

    // count phase
    int lsum = 0;
    for (int e = 0; e < CH; e++) {
        int g = base + e;
        if (g >= sn) break;
        int s = g / n, a = g - s * n;
        float i0 = xf[3*a]   + shifts[3*s];
        float i1 = xf[3*a+1] + shifts[3*s+1];
        float i2 = xf[3*a+2] + shifts[3*s+2];
        bool k = (i0 > 0.0f) && (i0 < bx0) &&
                 (i1 > 0.0f) && (i1 < bx1) &&
                 (i2 > 0.0f) && (i2 < bx2);
        if (k) lsum++;
    }
    sarr[t] = lsum;
    __syncthreads();
    for (int off = 1; off < 1024; off <<= 1) {
        int v = (t >= off) ? sarr[t - off] : 0;
        __syncthreads();
        sarr[t] += v;
        __syncthreads();
    }
    int pos = sarr[t] - lsum;

    // write phase (stable by construction: per-thread chunks are ordered)
    for (int e = 0; e < CH; e++) {
        int g = base + e;
        if (g >= sn) break;
        int s = g / n, a = g - s * n;
        float i0 = xf[3*a]   + shifts[3*s];
        float i1 = xf[3*a+1] + shifts[3*s+1];
        float i2 = xf[3*a+2] + shifts[3*s+2];
        bool k = (i0 > 0.0f) && (i0 < bx0) &&
                 (i1 > 0.0f) && (i1 < bx1) &&
                 (i2 > 0.0f) && (i2 < bx2);
        if (k) {
            int j = pos++;
            imgc[3*j] = i0; imgc[3*j+1] = i1; imgc[3*j+2] = i2;
            jshift[j] = s;
            jatom[j]  = a;
            float fc0 = floorf(i0 / CUT);
            float fc1 = floorf(i1 / CUT);
            float fc2 = floorf(i2 / CUT);
            float cf = fc2 * f10 + fc1 * mc0 + fc0;
            int ci = (int)cf;
            if (ci < 0) ci = 0;
            if (ci >= NCELLS) ci = NCELLS - 1;
            jcell[j] = ci;
            atomicAdd(&ccount[ci], 1);
        }
    }
    if (t == 1023) hdr_i[1] = sarr[1023];
}

// ---------------- K5a: exclusive scan of cell counts (single block) ----------------
__global__ __launch_bounds__(1024)
void k5_scan(const int* __restrict__ ccount, int* __restrict__ cstart)
{
    __shared__ int sarr[1024];
    int t = threadIdx.x;
    int b = t * 4;
    int v0 = ccount[b], v1 = ccount[b+1], v2 = ccount[b+2], v3 = ccount[b+3];
    int lsum = v0 + v1 + v2 + v3;
    sarr[t] = lsum;
    __syncthreads();
    for (int off = 1; off < 1024; off <<= 1) {
        int v = (t >= off) ? sarr[t - off] : 0;
        __syncthreads();
        sarr[t] += v;
        __syncthreads();
    }
    int excl = sarr[t] - lsum;
    cstart[b]   = excl;
    cstart[b+1] = excl + v0;
    cstart[b+2] = excl + v0 + v1;
    cstart[b+3] = excl + v0 + v1 + v2;
    if (t == 1023) cstart[NCELLS] = sarr[1023];
}

// ---------------- K5b: fill buckets (unordered; k8 rank-sorts by j) ----------------
__global__ __launch_bounds__(256)
void k5b_fill(const int* __restrict__ hdr_i, const int* __restrict__ jcell,
              const int* __restrict__ cstart, int* __restrict__ ccur,
              int* __restrict__ bucket, int SN)
{
    int j = blockIdx.x * 256 + threadIdx.x;
    if (j >= SN) return;
    if (j >= hdr_i[1]) return;
    int c = jcell[j];
    int w = cstart[c] + atomicAdd(&ccur[c], 1);
    bucket[w] = j;
}

// ---------------- K6: per-atom pair count — ONE WAVE PER ATOM ----------------
// 27 neighbor cells = 9 contiguous bucket ranges (x-adjacent cells are
// consecutive flat indices and cstart is contiguous), scanned 64-wide.
__global__ __launch_bounds__(256)
void k6_count(const int* __restrict__ hdr_i, const float* __restrict__ xf,
              const float* __restrict__ imgc, const int* __restrict__ cstart,
              const int* __restrict__ bucket, int* __restrict__ npair, int n)
{
    #pragma clang fp contract(off)
    int lane = threadIdx.x & 63;
    int atom = (blockIdx.x * 256 + threadIdx.x) >> 6;
    if (atom >= n) return;
    int mci = hdr_i[9], f10i = hdr_i[10];
    float x0 = xf[3*atom], x1 = xf[3*atom+1], x2 = xf[3*atom+2];
    int o0 = (int)floorf(x0 / CUT);
    int o1 = (int)floorf(x1 / CUT);
    int o2 = (int)floorf(x2 / CUT);
    int cnt = 0;
    for (int dz = -1; dz <= 1; dz++)
        for (int dy = -1; dy <= 1; dy++) {
            int nc0 = (o2+dz)*f10i + (o1+dy)*mci + (o0-1);
            int lo = nc0 < 0 ? 0 : nc0;
            int hi = nc0 + 3 > NCELLS ? NCELLS : nc0 + 3;
            if (lo >= hi) continue;
            int b0 = cstart[lo], b1 = cstart[hi];
            for (int b = b0 + lane; b < b1; b += 64) {
                int j = bucket[b];
                float dxx = x0 - imgc[3*j];
                float dyy = x1 - imgc[3*j+1];
                float dzz = x2 - imgc[3*j+2];
                float ss = dxx*dxx + dyy*dyy + dzz*dzz;
                float dd = sqrtf(ss);
                if (dd < CUT && dd > 0.001f) cnt++;
            }
        }
    #pragma unroll
    for (int off = 32; off > 0; off >>= 1)
        cnt += __shfl_down(cnt, off, 64);
    if (lane == 0) npair[atom] = cnt;
}

// ---------------- K7: exclusive scan over atoms (single block) ----------------
__global__ __launch_bounds__(1024)
void k7_scan(int* hdr_i, const int* __restrict__ npair, int* __restrict__ pstart, int n)
{
    __shared__ int sarr[1024];
    int t = threadIdx.x;
    int CH = (n + 1023) >> 10;
    int base = t * CH;
    int lsum = 0;
    for (int e = 0; e < CH; e++) {
        int g = base + e;
        if (g < n) lsum += npair[g];
    }
    sarr[t] = lsum;
    __syncthreads();
    for (int off = 1; off < 1024; off <<= 1) {
        int v = (t >= off) ? sarr[t - off] : 0;
        __syncthreads();
        sarr[t] += v;
        __syncthreads();
    }
    int run = sarr[t] - lsum;
    for (int e = 0; e < CH; e++) {
        int g = base + e;
        if (g < n) { pstart[g] = run; run += npair[g]; }
    }
    if (t == 1023) pstart[n] = sarr[1023];
    if (t == 0)    hdr_i[2]  = sarr[1023];
}

// ---------------- K8: emit — ONE WAVE PER ATOM, ballot-append + rank sort ----------------
__global__ __launch_bounds__(256)
void k8_emit(const int* __restrict__ hdr_i, const float* __restrict__ xf,
             const float* __restrict__ imgc, const int* __restrict__ jatom,
             const int* __restrict__ jshift, const float* __restrict__ shifts,
             const int* __restrict__ cstart, const int* __restrict__ bucket,
             const int* __restrict__ pstart, float* __restrict__ out,
             int n, int P)
{
    #pragma clang fp contract(off)
    __shared__ int lst[4][MAXNB];
    int w    = threadIdx.x >> 6;
    int lane = threadIdx.x & 63;
    int atom = blockIdx.x * 4 + w;
    bool valid = atom < n;

    int mci = hdr_i[9], f10i = hdr_i[10];
    float x0 = 0.f, x1 = 0.f, x2 = 0.f;
    if (valid) { x0 = xf[3*atom]; x1 = xf[3*atom+1]; x2 = xf[3*atom+2]; }
    int o0 = (int)floorf(x0 / CUT);
    int o1 = (int)floorf(x1 / CUT);
    int o2 = (int)floorf(x2 / CUT);

    int cnt = 0;
    if (valid) {
        for (int dz = -1; dz <= 1; dz++)
            for (int dy = -1; dy <= 1; dy++) {
                int nc0 = (o2+dz)*f10i + (o1+dy)*mci + (o0-1);
                int lo = nc0 < 0 ? 0 : nc0;
                int hi = nc0 + 3 > NCELLS ? NCELLS : nc0 + 3;
                if (lo >= hi) continue;
                int b0 = cstart[lo], b1 = cstart[hi];
                for (int bb = b0; bb < b1; bb += 64) {
                    int b = bb + lane;
                    bool ok = false; int j = 0;
                    if (b < b1) {
                        j = bucket[b];
                        float dxx = x0 - imgc[3*j];
                        float dyy = x1 - imgc[3*j+1];
                        float dzz = x2 - imgc[3*j+2];
                        float ss = dxx*dxx + dyy*dyy + dzz*dzz;
                        float dd = sqrtf(ss);
                        ok = (dd < CUT) && (dd > 0.001f);
                    }
                    unsigned long long m = __ballot(ok);
                    int posn = cnt + (int)__popcll(m & ((1ull << lane) - 1ull));
                    if (ok && posn < MAXNB) lst[w][posn] = j;
                    cnt += (int)__popcll(m);
                }
            }
        if (cnt > MAXNB) cnt = MAXNB;
    }
    __syncthreads();   // all threads reach (no early returns): LDS visibility

    if (valid) {
        int base = pstart[atom];
        for (int r = lane; r < cnt; r += 64) {
            int j = lst[w][r];
            int rank = 0;
            for (int q = 0; q < cnt; q++) rank += (lst[w][q] < j) ? 1 : 0;
            int p = base + rank;
            if (p < P) {
                out[p]     = (float)atom;
                out[P + p] = (float)jatom[j];
                int sp = jshift[j];
                out[2*P + 3*p]     = shifts[3*sp];
                out[2*P + 3*p + 1] = shifts[3*sp + 1];
                out[2*P + 3*p + 2] = shifts[3*sp + 2];
            }
        }
    }
}

extern "C" void kernel_launch(void* const* d_in, const int* in_sizes, int n_in,
                              void* d_out, int out_size, void* d_ws, size_t ws_size,
                              hipStream_t stream)
{
    const int*   period = (const int*)d_in[0];
    const float* coor   = (const float*)d_in[1];
    const float* cell   = (const float*)d_in[2];
    const float* mass   = (const float*)d_in[3];
    float* out = (float*)d_out;

    int n  = in_sizes[1] / 3;       // 2744
    int SN = S_CAP * n;             // 74088
    int P  = out_size / 5;          // pairs: neigh_list (2,P) + shifts (P,3)

    char* w = (char*)d_ws;
    size_t off = 0;
    auto alloc_f = [&](size_t cnt) -> float* { float* p = (float*)(w + off); off += cnt * 4; return p; };
    auto alloc_i = [&](size_t cnt) -> int*   { int*   p = (int*)  (w + off); off += cnt * 4; return p; };

    int*   hdr_i  = alloc_i(16);
    float* hdr_f  = alloc_f(16);
    float* shifts = alloc_f(3 * S_CAP);
    float* xf     = alloc_f(3 * (size_t)n);
    int*   jatom  = alloc_i(SN);
    int*   jshf   = alloc_i(SN);
    int*   jcell  = alloc_i(SN);
    float* imgc   = alloc_f(3 * (size_t)SN);
    int*   ccount = alloc_i(NCELLS);
    int*   ccur   = alloc_i(NCELLS);
    int*   cstart = alloc_i(NCELLS + 1);
    int*   bucket = alloc_i(SN);
    int*   npair  = alloc_i(n);
    int*   pstart = alloc_i(n + 1);
    (void)ws_size; (void)n_in;

    hipMemsetAsync(d_out, 0, (size_t)out_size * 4, stream);

    int nwb = (n + 3) / 4;  // wave-per-atom blocks (4 waves/block)

    hipLaunchKernelGGL(k1_pre,     dim3(1),            dim3(256),  0, stream,
                       period, coor, cell, mass, hdr_i, hdr_f, shifts, xf, n);
    hipLaunchKernelGGL(k3_compact, dim3(1),            dim3(1024), 0, stream,
                       hdr_i, hdr_f, shifts, xf, imgc, jatom, jshf, jcell, ccount, ccur, n, SN);
    hipLaunchKernelGGL(k5_scan,    dim3(1),            dim3(1024), 0, stream,
                       ccount, cstart);
    hipLaunchKernelGGL(k5b_fill,   dim3((SN+255)/256), dim3(256),  0, stream,
                       hdr_i, jcell, cstart, ccur, bucket, SN);
    hipLaunchKernelGGL(k6_count,   dim3(nwb),          dim3(256),  0, stream,
                       hdr_i, xf, imgc, cstart, bucket, npair, n);
    hipLaunchKernelGGL(k7_scan,    dim3(1),            dim3(1024), 0, stream,
                       hdr_i, npair, pstart, n);
    hipLaunchKernelGGL(k8_emit,    dim3(nwb),          dim3(256),  0, stream,
                       hdr_i, xf, imgc, jatom, jshf, shifts, cstart, bucket, pstart,
                       out, n, P);
}

// Round 4
// 108.693 us; speedup vs baseline: 7.2208x; 2.0985x over previous
//
#include <hip/hip_runtime.h>
#include <math.h>

#define S_CAP   27
#define NCELLS  4096
#define MAXNB   128
#define CUT     5.0f

// ---------------- K1: wrap coords, COM, min/max, shifts, header, zero counters ----------------
__global__ __launch_bounds__(256)
void k1_pre(const int* __restrict__ period, const float* __restrict__ coor,
            const float* __restrict__ cell, const float* __restrict__ mass,
            int* hdr_i, float* hdr_f, float* shifts, float* xf,
            int* __restrict__ ccount, int* __restrict__ ccur, int n)
{
    #pragma clang fp contract(off)
    __shared__ double rs[256 * 4];
    __shared__ float  redf[256 * 3];
    __shared__ float  s_com[3], s_m2[3];
    int t = threadIdx.x;

    // zero cell counters (no dependency on the rest)
    for (int c = t; c < NCELLS; c += 256) { ccount[c] = 0; ccur[c] = 0; }

    float c[3][3];
    #pragma unroll
    for (int i = 0; i < 3; i++)
        #pragma unroll
        for (int j = 0; j < 3; j++) c[i][j] = cell[3 * i + j];

    // analytic inverse (exact for diagonal cell)
    float a00 = c[1][1]*c[2][2] - c[1][2]*c[2][1];
    float a01 = c[0][2]*c[2][1] - c[0][1]*c[2][2];
    float a02 = c[0][1]*c[1][2] - c[0][2]*c[1][1];
    float a10 = c[1][2]*c[2][0] - c[1][0]*c[2][2];
    float a11 = c[0][0]*c[2][2] - c[0][2]*c[2][0];
    float a12 = c[0][2]*c[1][0] - c[0][0]*c[1][2];
    float a20 = c[1][0]*c[2][1] - c[1][1]*c[2][0];
    float a21 = c[0][1]*c[2][0] - c[0][0]*c[2][1];
    float a22 = c[0][0]*c[1][1] - c[0][1]*c[1][0];
    float det = c[0][0]*a00 + c[0][1]*a10 + c[0][2]*a20;
    float inv[3][3] = {{a00/det, a01/det, a02/det},
                       {a10/det, a11/det, a12/det},
                       {a20/det, a21/det, a22/det}};

    float f0[3];
    #pragma unroll
    for (int d = 0; d < 3; d++)
        f0[d] = coor[0]*inv[0][d] + coor[1]*inv[1][d] + coor[2]*inv[2][d];

    // pass 1: wrap into cell, store cartesian, accumulate mass sums (fp64)
    double sm = 0.0, sx = 0.0, sy = 0.0, sz = 0.0;
    for (int i = t; i < n; i += 256) {
        float p0 = coor[3*i], p1 = coor[3*i+1], p2 = coor[3*i+2];
        float ic[3], w[3], x[3];
        #pragma unroll
        for (int d = 0; d < 3; d++)
            ic[d] = p0*inv[0][d] + p1*inv[1][d] + p2*inv[2][d];
        #pragma unroll
        for (int d = 0; d < 3; d++)
            w[d] = ic[d] - rintf(ic[d] - f0[d]);
        #pragma unroll
        for (int d = 0; d < 3; d++)
            x[d] = w[0]*c[0][d] + w[1]*c[1][d] + w[2]*c[2][d];
        xf[3*i] = x[0]; xf[3*i+1] = x[1]; xf[3*i+2] = x[2];
        float m = mass[i];
        sm += (double)m;
        sx += (double)m * (double)x[0];
        sy += (double)m * (double)x[1];
        sz += (double)m * (double)x[2];
    }
    rs[t] = sm; rs[256+t] = sx; rs[512+t] = sy; rs[768+t] = sz;
    __syncthreads();
    for (int off = 128; off > 0; off >>= 1) {
        if (t < off) {
            rs[t]       += rs[t+off];
            rs[256+t]   += rs[256+t+off];
            rs[512+t]   += rs[512+t+off];
            rs[768+t]   += rs[768+t+off];
        }
        __syncthreads();
    }
    if (t == 0) {
        float den = (float)rs[0];
        s_com[0] = ((float)rs[256]) / den;
        s_com[1] = ((float)rs[512]) / den;
        s_com[2] = ((float)rs[768]) / den;
    }
    __syncthreads();
    float com0 = s_com[0], com1 = s_com[1], com2 = s_com[2];

    // pass 2: subtract COM, per-dim min
    float mn0 = __builtin_inff(), mn1 = __builtin_inff(), mn2 = __builtin_inff();
    for (int i = t; i < n; i += 256) {
        float v0 = xf[3*i]   - com0;
        float v1 = xf[3*i+1] - com1;
        float v2 = xf[3*i+2] - com2;
        xf[3*i] = v0; xf[3*i+1] = v1; xf[3*i+2] = v2;
        mn0 = fminf(mn0, v0); mn1 = fminf(mn1, v1); mn2 = fminf(mn2, v2);
    }
    redf[t] = mn0; redf[256+t] = mn1; redf[512+t] = mn2;
    __syncthreads();
    for (int off = 128; off > 0; off >>= 1) {
        if (t < off) {
            redf[t]     = fminf(redf[t],     redf[t+off]);
            redf[256+t] = fminf(redf[256+t], redf[256+t+off]);
            redf[512+t] = fminf(redf[512+t], redf[512+t+off]);
        }
        __syncthreads();
    }
    if (t == 0) {
        s_m2[0] = (redf[0]   - CUT) - 1e-6f;
        s_m2[1] = (redf[256] - CUT) - 1e-6f;
        s_m2[2] = (redf[512] - CUT) - 1e-6f;
    }
    __syncthreads();
    float m20 = s_m2[0], m21 = s_m2[1], m22 = s_m2[2];

    // pass 3: shift to positive box, per-dim max
    float mx0 = -__builtin_inff(), mx1 = -__builtin_inff(), mx2 = -__builtin_inff();
    for (int i = t; i < n; i += 256) {
        float v0 = xf[3*i]   - m20;
        float v1 = xf[3*i+1] - m21;
        float v2 = xf[3*i+2] - m22;
        xf[3*i] = v0; xf[3*i+1] = v1; xf[3*i+2] = v2;
        mx0 = fmaxf(mx0, v0); mx1 = fmaxf(mx1, v1); mx2 = fmaxf(mx2, v2);
    }
    redf[t] = mx0; redf[256+t] = mx1; redf[512+t] = mx2;
    __syncthreads();
    for (int off = 128; off > 0; off >>= 1) {
        if (t < off) {
            redf[t]     = fmaxf(redf[t],     redf[t+off]);
            redf[256+t] = fmaxf(redf[256+t], redf[256+t+off]);
            redf[512+t] = fmaxf(redf[512+t], redf[512+t+off]);
        }
        __syncthreads();
    }
    if (t == 0) {
        float maxc0 = redf[0]   + CUT;
        float maxc1 = redf[256] + CUT;
        float maxc2 = redf[512] + CUT;
        float mcell0 = ceilf(maxc0 / CUT);
        float mcell1 = ceilf(maxc1 / CUT);
        float f10 = mcell1 * mcell0;
        int nr[3];
        for (int j = 0; j < 3; j++) {
            float v = __builtin_inff();
            for (int i = 0; i < 3; i++) {
                float q = CUT / fabsf(c[i][j]);   // IEEE: /0 -> inf
                v = fminf(v, q);
            }
            nr[j] = (int)ceilf(v);
            nr[j] *= period[j];
        }
        int nsz0 = 2*nr[0]+1, nsz1 = 2*nr[1]+1, nsz2 = 2*nr[2]+1;
        int S = nsz0 * nsz1 * nsz2;
        if (S > S_CAP) S = S_CAP;
        hdr_i[0] = S;
        hdr_i[3] = -nr[0]; hdr_i[4] = -nr[1]; hdr_i[5] = -nr[2];
        hdr_i[6] = nsz0;   hdr_i[7] = nsz1;   hdr_i[8] = nsz2;
        hdr_i[9]  = (int)mcell0;
        hdr_i[10] = (int)f10;
        hdr_f[0] = maxc0; hdr_f[1] = maxc1; hdr_f[2] = maxc2;
        hdr_f[3] = f10;   hdr_f[4] = mcell0;
    }
    __syncthreads();
    int S = hdr_i[0];
    if (t < S) {
        int n1 = hdr_i[7], n2 = hdr_i[8];
        int i0 = t / (n1 * n2);
        int rem = t - i0 * n1 * n2;
        int i1 = rem / n2;
        int i2 = rem - i1 * n2;
        float fx = (float)(hdr_i[3] + i0);
        float fy = (float)(hdr_i[4] + i1);
        float fz = (float)(hdr_i[5] + i2);
        #pragma unroll
        for (int d = 0; d < 3; d++)
            shifts[3*t + d] = fx*c[0][d] + fy*c[1][d] + fz*c[2][d];
    }
}

// ---------------- K2: per-image cell histogram (multi-block, image on the fly) ----------------
__global__ __launch_bounds__(256)
void k2_count(const int* __restrict__ hdr_i, const float* __restrict__ hdr_f,
              const float* __restrict__ shifts, const float* __restrict__ xf,
              int* __restrict__ ccount, int n)
{
    #pragma clang fp contract(off)
    int g = blockIdx.x * 256 + threadIdx.x;
    int sn = hdr_i[0] * n;
    if (g >= sn) return;
    int s = g / n, a = g - s * n;
    float i0 = xf[3*a]   + shifts[3*s];
    float i1 = xf[3*a+1] + shifts[3*s+1];
    float i2 = xf[3*a+2] + shifts[3*s+2];
    bool k = (i0 > 0.0f) && (i0 < hdr_f[0]) &&
             (i1 > 0.0f) && (i1 < hdr_f[1]) &&
             (i2 > 0.0f) && (i2 < hdr_f[2]);
    if (!k) return;
    float fc0 = floorf(i0 / CUT);
    float fc1 = floorf(i1 / CUT);
    float fc2 = floorf(i2 / CUT);
    float cf = fc2 * hdr_f[3] + fc1 * hdr_f[4] + fc0;
    int ci = (int)cf;
    if (ci < 0) ci = 0;
    if (ci >= NCELLS) ci = NCELLS - 1;
    atomicAdd(&ccount[ci], 1);
}

// ---------------- K5a: exclusive scan of cell counts (single block) ----------------
__global__ __launch_bounds__(1024)
void k5_scan(const int* __restrict__ ccount, int* __restrict__ cstart)
{
    __shared__ int sarr[1024];
    int t = threadIdx.x;
    int b = t * 4;
    int v0 = ccount[b], v1 = ccount[b+1], v2 = ccount[b+2], v3 = ccount[b+3];
    int lsum = v0 + v1 + v2 + v3;
    sarr[t] = lsum;
    __syncthreads();
    for (int off = 1; off < 1024; off <<= 1) {
        int v = (t >= off) ? sarr[t - off] : 0;
        __syncthreads();
        sarr[t] += v;
        __syncthreads();
    }
    int excl = sarr[t] - lsum;
    cstart[b]   = excl;
    cstart[b+1] = excl + v0;
    cstart[b+2] = excl + v0 + v1;
    cstart[b+3] = excl + v0 + v1 + v2;
    if (t == 1023) cstart[NCELLS] = sarr[1023];
}

// ---------------- K5b: fill buckets with float4{x,y,z,g} (unordered) ----------------
__global__ __launch_bounds__(256)
void k5b_fill(const int* __restrict__ hdr_i, const float* __restrict__ hdr_f,
              const float* __restrict__ shifts, const float* __restrict__ xf,
              const int* __restrict__ cstart, int* __restrict__ ccur,
              float4* __restrict__ bucket4, int n)
{
    #pragma clang fp contract(off)
    int g = blockIdx.x * 256 + threadIdx.x;
    int sn = hdr_i[0] * n;
    if (g >= sn) return;
    int s = g / n, a = g - s * n;
    float i0 = xf[3*a]   + shifts[3*s];
    float i1 = xf[3*a+1] + shifts[3*s+1];
    float i2 = xf[3*a+2] + shifts[3*s+2];
    bool k = (i0 > 0.0f) && (i0 < hdr_f[0]) &&
             (i1 > 0.0f) && (i1 < hdr_f[1]) &&
             (i2 > 0.0f) && (i2 < hdr_f[2]);
    if (!k) return;
    float fc0 = floorf(i0 / CUT);
    float fc1 = floorf(i1 / CUT);
    float fc2 = floorf(i2 / CUT);
    float cf = fc2 * hdr_f[3] + fc1 * hdr_f[4] + fc0;
    int ci = (int)cf;
    if (ci < 0) ci = 0;
    if (ci >= NCELLS) ci = NCELLS - 1;
    int w = cstart[ci] + atomicAdd(&ccur[ci], 1);
    bucket4[w] = make_float4(i0, i1, i2, __int_as_float(g));
}

// ---------------- K6: per-atom pair count — one wave per atom ----------------
__global__ __launch_bounds__(256)
void k6_count(const int* __restrict__ hdr_i, const float* __restrict__ xf,
              const int* __restrict__ cstart, const float4* __restrict__ bucket4,
              int* __restrict__ npair, int n)
{
    #pragma clang fp contract(off)
    int lane = threadIdx.x & 63;
    int atom = (blockIdx.x * 256 + threadIdx.x) >> 6;
    if (atom >= n) return;
    int mci = hdr_i[9], f10i = hdr_i[10];
    float x0 = xf[3*atom], x1 = xf[3*atom+1], x2 = xf[3*atom+2];
    int o0 = (int)floorf(x0 / CUT);
    int o1 = (int)floorf(x1 / CUT);
    int o2 = (int)floorf(x2 / CUT);
    int cnt = 0;
    for (int dz = -1; dz <= 1; dz++)
        for (int dy = -1; dy <= 1; dy++) {
            int nc0 = (o2+dz)*f10i + (o1+dy)*mci + (o0-1);
            int lo = nc0 < 0 ? 0 : nc0;
            int hi = nc0 + 3 > NCELLS ? NCELLS : nc0 + 3;
            if (lo >= hi) continue;
            int b0 = cstart[lo], b1 = cstart[hi];
            for (int b = b0 + lane; b < b1; b += 64) {
                float4 v = bucket4[b];
                float dxx = x0 - v.x;
                float dyy = x1 - v.y;
                float dzz = x2 - v.z;
                float ss = dxx*dxx + dyy*dyy + dzz*dzz;
                float dd = sqrtf(ss);
                if (dd < CUT && dd > 0.001f) cnt++;
            }
        }
    #pragma unroll
    for (int off = 32; off > 0; off >>= 1)
        cnt += __shfl_down(cnt, off, 64);
    if (lane == 0) npair[atom] = cnt;
}

// ---------------- K7: exclusive scan over atoms (single block) ----------------
__global__ __launch_bounds__(1024)
void k7_scan(int* hdr_i, const int* __restrict__ npair, int* __restrict__ pstart, int n)
{
    __shared__ int sarr[1024];
    int t = threadIdx.x;
    int CH = (n + 1023) >> 10;
    int base = t * CH;
    int lsum = 0;
    for (int e = 0; e < CH; e++) {
        int g = base + e;
        if (g < n) lsum += npair[g];
    }
    sarr[t] = lsum;
    __syncthreads();
    for (int off = 1; off < 1024; off <<= 1) {
        int v = (t >= off) ? sarr[t - off] : 0;
        __syncthreads();
        sarr[t] += v;
        __syncthreads();
    }
    int run = sarr[t] - lsum;
    for (int e = 0; e < CH; e++) {
        int g = base + e;
        if (g < n) { pstart[g] = run; run += npair[g]; }
    }
    if (t == 1023) pstart[n] = sarr[1023];
    if (t == 0)    hdr_i[2]  = sarr[1023];
}

// ---------------- K8: emit — one wave per atom, ballot-append + rank sort by g ----------------
__global__ __launch_bounds__(256)
void k8_emit(const int* __restrict__ hdr_i, const float* __restrict__ xf,
             const float* __restrict__ shifts, const int* __restrict__ cstart,
             const float4* __restrict__ bucket4, const int* __restrict__ pstart,
             float* __restrict__ out, int n, int P)
{
    #pragma clang fp contract(off)
    __shared__ int lst[4][MAXNB];
    int w    = threadIdx.x >> 6;
    int lane = threadIdx.x & 63;
    int atom = blockIdx.x * 4 + w;
    bool valid = atom < n;

    int mci = hdr_i[9], f10i = hdr_i[10];
    float x0 = 0.f, x1 = 0.f, x2 = 0.f;
    if (valid) { x0 = xf[3*atom]; x1 = xf[3*atom+1]; x2 = xf[3*atom+2]; }
    int o0 = (int)floorf(x0 / CUT);
    int o1 = (int)floorf(x1 / CUT);
    int o2 = (int)floorf(x2 / CUT);

    int cnt = 0;
    if (valid) {
        for (int dz = -1; dz <= 1; dz++)
            for (int dy = -1; dy <= 1; dy++) {
                int nc0 = (o2+dz)*f10i + (o1+dy)*mci + (o0-1);
                int lo = nc0 < 0 ? 0 : nc0;
                int hi = nc0 + 3 > NCELLS ? NCELLS : nc0 + 3;
                if (lo >= hi) continue;
                int b0 = cstart[lo], b1 = cstart[hi];
                for (int bb = b0; bb < b1; bb += 64) {
                    int b = bb + lane;
                    bool ok = false; int g = 0;
                    if (b < b1) {
                        float4 v = bucket4[b];
                        g = __float_as_int(v.w);
                        float dxx = x0 - v.x;
                        float dyy = x1 - v.y;
                        float dzz = x2 - v.z;
                        float ss = dxx*dxx + dyy*dyy + dzz*dzz;
                        float dd = sqrtf(ss);
                        ok = (dd < CUT) && (dd > 0.001f);
                    }
                    unsigned long long m = __ballot(ok);
                    int posn = cnt + (int)__popcll(m & ((1ull << lane) - 1ull));
                    if (ok && posn < MAXNB) lst[w][posn] = g;
                    cnt += (int)__popcll(m);
                }
            }
        if (cnt > MAXNB) cnt = MAXNB;
    }
    __syncthreads();   // all threads reach (no early returns): LDS visibility

    if (valid) {
        int base = pstart[atom];
        for (int r = lane; r < cnt; r += 64) {
            int g = lst[w][r];
            int rank = 0;
            for (int q = 0; q < cnt; q++) rank += (lst[w][q] < g) ? 1 : 0;
            int p = base + rank;
            if (p < P) {
                int s = g / n;
                int a = g - s * n;
                out[p]     = (float)atom;
                out[P + p] = (float)a;
                out[2*P + 3*p]     = shifts[3*s];
                out[2*P + 3*p + 1] = shifts[3*s + 1];
                out[2*P + 3*p + 2] = shifts[3*s + 2];
            }
        }
    }
}

extern "C" void kernel_launch(void* const* d_in, const int* in_sizes, int n_in,
                              void* d_out, int out_size, void* d_ws, size_t ws_size,
                              hipStream_t stream)
{
    const int*   period = (const int*)d_in[0];
    const float* coor   = (const float*)d_in[1];
    const float* cell   = (const float*)d_in[2];
    const float* mass   = (const float*)d_in[3];
    float* out = (float*)d_out;

    int n  = in_sizes[1] / 3;       // 2744
    int SN = S_CAP * n;             // 74088
    int P  = out_size / 5;          // pairs: neigh_list (2,P) + shifts (P,3)

    char* w = (char*)d_ws;
    size_t off = 0;
    auto alloc = [&](size_t bytes) -> void* {
        off = (off + 15) & ~(size_t)15;
        void* p = (void*)(w + off); off += bytes; return p;
    };

    int*    hdr_i   = (int*)   alloc(16 * 4);
    float*  hdr_f   = (float*) alloc(16 * 4);
    float*  shifts  = (float*) alloc(3 * S_CAP * 4);
    float*  xf      = (float*) alloc(3 * (size_t)n * 4);
    int*    ccount  = (int*)   alloc(NCELLS * 4);
    int*    ccur    = (int*)   alloc(NCELLS * 4);
    int*    cstart  = (int*)   alloc((NCELLS + 1) * 4);
    float4* bucket4 = (float4*)alloc((size_t)SN * 16);
    int*    npair   = (int*)   alloc((size_t)n * 4);
    int*    pstart  = (int*)   alloc(((size_t)n + 1) * 4);
    (void)ws_size; (void)n_in;

    hipMemsetAsync(d_out, 0, (size_t)out_size * 4, stream);

    int nwb = (n + 3) / 4;  // wave-per-atom blocks (4 waves/block)

    hipLaunchKernelGGL(k1_pre,   dim3(1),            dim3(256),  0, stream,
                       period, coor, cell, mass, hdr_i, hdr_f, shifts, xf, ccount, ccur, n);
    hipLaunchKernelGGL(k2_count, dim3((SN+255)/256), dim3(256),  0, stream,
                       hdr_i, hdr_f, shifts, xf, ccount, n);
    hipLaunchKernelGGL(k5_scan,  dim3(1),            dim3(1024), 0, stream,
                       ccount, cstart);
    hipLaunchKernelGGL(k5b_fill, dim3((SN+255)/256), dim3(256),  0, stream,
                       hdr_i, hdr_f, shifts, xf, cstart, ccur, bucket4, n);
    hipLaunchKernelGGL(k6_count, dim3(nwb),          dim3(256),  0, stream,
                       hdr_i, xf, cstart, bucket4, npair, n);
    hipLaunchKernelGGL(k7_scan,  dim3(1),            dim3(1024), 0, stream,
                       hdr_i, npair, pstart, n);
    hipLaunchKernelGGL(k8_emit,  dim3(nwb),          dim3(256),  0, stream,
                       hdr_i, xf, shifts, cstart, bucket4, pstart, out, n, P);
}